// Round 1
// baseline (1541.677 us; speedup 1.0000x reference)
//
#include <hip/hip_runtime.h>

typedef __attribute__((ext_vector_type(8))) short bf8;
typedef __attribute__((ext_vector_type(4))) float f4;

__device__ __forceinline__ ushort f2b(float f) {
  union { float f; unsigned u; } v; v.f = f;
  unsigned u = v.u + 0x7FFFu + ((v.u >> 16) & 1u);
  return (ushort)(u >> 16);
}
__device__ __forceinline__ float b2f(ushort h) {
  union { unsigned u; float f; } v; v.u = ((unsigned)h) << 16; return v.f;
}
__device__ __forceinline__ bf8 pack8(const float* p) {
  f4 a = *(const f4*)p; f4 b = *(const f4*)(p + 4);
  bf8 t;
  t[0] = (short)f2b(a[0]); t[1] = (short)f2b(a[1]);
  t[2] = (short)f2b(a[2]); t[3] = (short)f2b(a[3]);
  t[4] = (short)f2b(b[0]); t[5] = (short)f2b(b[1]);
  t[6] = (short)f2b(b[2]); t[7] = (short)f2b(b[3]);
  return t;
}
__device__ __forceinline__ float sigm(float x) { return 1.f / (1.f + __expf(-x)); }
__device__ __forceinline__ float tanh_f(float x) {
  float a = fabsf(x), e = __expf(-2.f * a);
  return copysignf((1.f - e) / (1.f + e), x);
}

// ---------------- f32 -> bf16 convert ----------------
__global__ __launch_bounds__(256) void cvt_k(const float* __restrict__ in,
                                             ushort* __restrict__ out, int n4) {
  int i = blockIdx.x * 256 + threadIdx.x;
  if (i < n4) {
    f4 v = ((const f4*)in)[i];
    ushort4 o;
    o.x = f2b(v[0]); o.y = f2b(v[1]); o.z = f2b(v[2]); o.w = f2b(v[3]);
    ((ushort4*)out)[i] = o;
  }
}

// ---------------- generic bf16 MFMA GEMM ----------------
// C[z] = op( A @ B[z] + bias + Cin[z] ), A row-major (M x K) bf16.
// TRANSB=1: B is (N x K) row-major (torch weight layout). TRANSB=0: B is (K x N).
template<int TRANSB, int HAS_BIAS, int RELU, int HAS_CIN, int OUT_BF>
__global__ __launch_bounds__(256) void gemm_k(
    const ushort* __restrict__ A, const ushort* __restrict__ B,
    void* __restrict__ Cv, const float* __restrict__ Cin,
    const float* __restrict__ bias, int biasMask,
    int M, int N, int K, int lda, int ldb, int ldc,
    long sBz, long sCz, long sCinz)
{
  __shared__ ushort As[128][88];
  __shared__ ushort Bs[128][88];
  const int tid = threadIdx.x, lane = tid & 63, wv = tid >> 6;
  const int wm = wv >> 1, wn = wv & 1;
  const int bm = blockIdx.x * 128, bn = blockIdx.y * 128;
  const long zB = (long)blockIdx.z * sBz;
  const long zC = (long)blockIdx.z * sCz;
  f4 acc[4][4] = {};
  for (int k0 = 0; k0 < K; k0 += 64) {
    #pragma unroll
    for (int it = 0; it < 4; ++it) {
      int row = (tid >> 3) + 32 * it;
      int ch  = (tid & 7) * 8;
      *(int4*)(&As[row][ch]) = *(const int4*)(A + (long)(bm + row) * lda + k0 + ch);
    }
    if (TRANSB) {
      #pragma unroll
      for (int it = 0; it < 4; ++it) {
        int row = (tid >> 3) + 32 * it;
        int ch  = (tid & 7) * 8;
        int4 v = {0, 0, 0, 0};
        if (bn + row < N) v = *(const int4*)(B + zB + (long)(bn + row) * ldb + k0 + ch);
        *(int4*)(&Bs[row][ch]) = v;
      }
    } else {
      #pragma unroll
      for (int nb = 0; nb < 4; ++nb) {
        int nc = (tid & 31) + 32 * nb;
        #pragma unroll
        for (int it = 0; it < 8; ++it) {
          int kr = (tid >> 5) + 8 * it;
          ushort v = 0;
          if (bn + nc < N) v = B[zB + (long)(k0 + kr) * ldb + bn + nc];
          Bs[nc][kr] = v;
        }
      }
    }
    __syncthreads();
    bf8 af[4][2], bfv[4][2];
    #pragma unroll
    for (int mi = 0; mi < 4; ++mi)
      #pragma unroll
      for (int kk = 0; kk < 2; ++kk)
        af[mi][kk] = *(const bf8*)(&As[wm * 64 + mi * 16 + (lane & 15)][kk * 32 + (lane >> 4) * 8]);
    #pragma unroll
    for (int ni = 0; ni < 4; ++ni)
      #pragma unroll
      for (int kk = 0; kk < 2; ++kk)
        bfv[ni][kk] = *(const bf8*)(&Bs[wn * 64 + ni * 16 + (lane & 15)][kk * 32 + (lane >> 4) * 8]);
    #pragma unroll
    for (int kk = 0; kk < 2; ++kk)
      #pragma unroll
      for (int mi = 0; mi < 4; ++mi)
        #pragma unroll
        for (int ni = 0; ni < 4; ++ni)
          acc[mi][ni] = __builtin_amdgcn_mfma_f32_16x16x32_bf16(af[mi][kk], bfv[ni][kk], acc[mi][ni], 0, 0, 0);
    __syncthreads();
  }
  #pragma unroll
  for (int mi = 0; mi < 4; ++mi) {
    #pragma unroll
    for (int ni = 0; ni < 4; ++ni) {
      int col = bn + wn * 64 + ni * 16 + (lane & 15);
      if (col < N) {
        #pragma unroll
        for (int r = 0; r < 4; ++r) {
          int row = bm + wm * 64 + mi * 16 + (lane >> 4) * 4 + r;
          float v = acc[mi][ni][r];
          if (HAS_CIN) v += Cin[(long)blockIdx.z * sCinz + (long)row * ldc + col];
          if (HAS_BIAS) v += bias[col & biasMask];
          if (RELU) v = fmaxf(v, 0.f);
          if (OUT_BF) ((ushort*)Cv)[zC + (long)row * ldc + col] = f2b(v);
          else        ((float*)Cv)[zC + (long)row * ldc + col] = v;
        }
      }
    }
  }
}

// ---------------- fused 2-layer GRU ----------------
// 32 sequences / block, T=32, hidden 64. Weights held as MFMA B-fragments in
// registers (wave w owns output columns [16w,16w+16) of each gate).
__global__ __launch_bounds__(256) void gru_k(
    const ushort* __restrict__ x,
    const float* __restrict__ Wx0, const float* __restrict__ Wh0,
    const float* __restrict__ bx0, const float* __restrict__ bh0,
    const float* __restrict__ Wx1, const float* __restrict__ Wh1,
    const float* __restrict__ bx1, const float* __restrict__ bh1,
    ushort* __restrict__ rout)
{
  __shared__ ushort hbf[2][32][88];
  __shared__ float  hf[2][32][68];
  const int tid = threadIdx.x, lane = tid & 63, w = tid >> 6;
  const long seq0 = (long)blockIdx.x * 32;
  for (int i = tid; i < 2 * 32 * 88; i += 256) ((ushort*)hbf)[i] = 0;
  for (int i = tid; i < 2 * 32 * 68; i += 256) ((float*)hf)[i] = 0.f;

  const float* Wxp[2] = {Wx0, Wx1};
  const float* Whp[2] = {Wh0, Wh1};
  const float* bxp[2] = {bx0, bx1};
  const float* bhp[2] = {bh0, bh1};
  bf8 Wxf[2][3][2], Whf[2][3][2];
  float bxv[2][3], bhv[2][3];
  #pragma unroll
  for (int L = 0; L < 2; ++L)
    #pragma unroll
    for (int g = 0; g < 3; ++g) {
      int row = g * 64 + w * 16 + (lane & 15);
      bxv[L][g] = bxp[L][row];
      bhv[L][g] = bhp[L][row];
      #pragma unroll
      for (int kk = 0; kk < 2; ++kk) {
        int kb = kk * 32 + (lane >> 4) * 8;
        Wxf[L][g][kk] = pack8(Wxp[L] + row * 64 + kb);
        Whf[L][g][kk] = pack8(Whp[L] + row * 64 + kb);
      }
    }
  __syncthreads();

  for (int t = 0; t < 32; ++t) {
    #pragma unroll
    for (int L = 0; L < 2; ++L) {
      bf8 ax[2][2], ah[2][2];
      #pragma unroll
      for (int mi = 0; mi < 2; ++mi)
        #pragma unroll
        for (int kk = 0; kk < 2; ++kk) {
          int row = mi * 16 + (lane & 15);
          int kb = kk * 32 + (lane >> 4) * 8;
          if (L == 0) ax[mi][kk] = *(const bf8*)(x + ((seq0 + row) * 32 + t) * 64 + kb);
          else        ax[mi][kk] = *(const bf8*)(&hbf[0][row][kb]);
          ah[mi][kk] = *(const bf8*)(&hbf[L][row][kb]);
        }
      f4 aX[2][3] = {}; f4 aH[2][3] = {};
      #pragma unroll
      for (int kk = 0; kk < 2; ++kk)
        #pragma unroll
        for (int mi = 0; mi < 2; ++mi)
          #pragma unroll
          for (int g = 0; g < 3; ++g) {
            aX[mi][g] = __builtin_amdgcn_mfma_f32_16x16x32_bf16(ax[mi][kk], Wxf[L][g][kk], aX[mi][g], 0, 0, 0);
            aH[mi][g] = __builtin_amdgcn_mfma_f32_16x16x32_bf16(ah[mi][kk], Whf[L][g][kk], aH[mi][g], 0, 0, 0);
          }
      __syncthreads();  // all reads of hbf/hf done before writes
      #pragma unroll
      for (int mi = 0; mi < 2; ++mi)
        #pragma unroll
        for (int r = 0; r < 4; ++r) {
          int row = mi * 16 + (lane >> 4) * 4 + r;
          int col = w * 16 + (lane & 15);
          float rg = sigm(aX[mi][0][r] + bxv[L][0] + aH[mi][0][r] + bhv[L][0]);
          float zg = sigm(aX[mi][1][r] + bxv[L][1] + aH[mi][1][r] + bhv[L][1]);
          float hn = aH[mi][2][r] + bhv[L][2];
          float cand = tanh_f(aX[mi][2][r] + bxv[L][2] + rg * hn);
          float hp = hf[L][row][col];
          float hnew = (1.f - zg) * cand + zg * hp;
          hf[L][row][col] = hnew;
          ushort hb = f2b(hnew);
          hbf[L][row][col] = hb;
          if (L == 1) rout[((seq0 + row) * 32 + t) * 64 + col] = hb;
        }
      __syncthreads();
    }
  }
}

// ---------------- fused temporal attention + residual + LayerNorm ----------------
// One block per sequence (T=32), wave w = head w (4 heads, d=16).
__global__ __launch_bounds__(256) void attn_k(
    const ushort* __restrict__ r,
    const float* __restrict__ Wq, const float* __restrict__ Wk,
    const float* __restrict__ Wv, const float* __restrict__ Wo,
    const float* __restrict__ lng, const float* __restrict__ lnb,
    ushort* __restrict__ enc)
{
  __shared__ ushort q_s[4][32][40];
  __shared__ ushort k_s[4][32][40];
  __shared__ ushort v_s[4][16][40];
  __shared__ ushort p_s[4][32][40];
  __shared__ ushort o_s[32][88];
  __shared__ float  ln_s[32][68];
  const int tid = threadIdx.x, lane = tid & 63, w = tid >> 6;
  const long n = blockIdx.x;

  for (int i = tid; i < 4 * 32 * 40; i += 256) { ((ushort*)q_s)[i] = 0; ((ushort*)k_s)[i] = 0; }

  bf8 wqf[2], wkf[2], wvf[2], wof[2];
  #pragma unroll
  for (int kk = 0; kk < 2; ++kk) {
    int row = w * 16 + (lane & 15);
    int kb = kk * 32 + (lane >> 4) * 8;
    wqf[kk] = pack8(Wq + row * 64 + kb);
    wkf[kk] = pack8(Wk + row * 64 + kb);
    wvf[kk] = pack8(Wv + row * 64 + kb);
    wof[kk] = pack8(Wo + row * 64 + kb);
  }
  __syncthreads();  // zero-init visible

  // QKV projections
  bf8 ar[2][2];
  #pragma unroll
  for (int mi = 0; mi < 2; ++mi)
    #pragma unroll
    for (int kk = 0; kk < 2; ++kk)
      ar[mi][kk] = *(const bf8*)(r + (n * 32 + mi * 16 + (lane & 15)) * 64 + kk * 32 + (lane >> 4) * 8);
  f4 aq[2] = {}, ak[2] = {}, av[2] = {};
  #pragma unroll
  for (int kk = 0; kk < 2; ++kk)
    #pragma unroll
    for (int mi = 0; mi < 2; ++mi) {
      aq[mi] = __builtin_amdgcn_mfma_f32_16x16x32_bf16(ar[mi][kk], wqf[kk], aq[mi], 0, 0, 0);
      ak[mi] = __builtin_amdgcn_mfma_f32_16x16x32_bf16(ar[mi][kk], wkf[kk], ak[mi], 0, 0, 0);
      av[mi] = __builtin_amdgcn_mfma_f32_16x16x32_bf16(ar[mi][kk], wvf[kk], av[mi], 0, 0, 0);
    }
  #pragma unroll
  for (int mi = 0; mi < 2; ++mi)
    #pragma unroll
    for (int rr = 0; rr < 4; ++rr) {
      int row = mi * 16 + (lane >> 4) * 4 + rr;
      q_s[w][row][lane & 15] = f2b(aq[mi][rr]);
      k_s[w][row][lane & 15] = f2b(ak[mi][rr]);
      v_s[w][lane & 15][row] = f2b(av[mi][rr]);   // transposed: [d][t']
    }

  // S = Q K^T * 0.25, causal mask, softmax (per-head, wave-private LDS)
  bf8 a_q[2], b_k[2];
  #pragma unroll
  for (int mt = 0; mt < 2; ++mt)
    a_q[mt] = *(const bf8*)(&q_s[w][mt * 16 + (lane & 15)][(lane >> 4) * 8]);
  #pragma unroll
  for (int nt = 0; nt < 2; ++nt)
    b_k[nt] = *(const bf8*)(&k_s[w][nt * 16 + (lane & 15)][(lane >> 4) * 8]);
  f4 s_[2][2] = {};
  #pragma unroll
  for (int mt = 0; mt < 2; ++mt)
    #pragma unroll
    for (int nt = 0; nt < 2; ++nt)
      s_[mt][nt] = __builtin_amdgcn_mfma_f32_16x16x32_bf16(a_q[mt], b_k[nt], s_[mt][nt], 0, 0, 0);
  #pragma unroll
  for (int mt = 0; mt < 2; ++mt)
    #pragma unroll
    for (int rr = 0; rr < 4; ++rr) {
      int trow = mt * 16 + (lane >> 4) * 4 + rr;
      float s0 = s_[mt][0][rr] * 0.25f, s1 = s_[mt][1][rr] * 0.25f;
      int c0 = lane & 15, c1 = 16 + (lane & 15);
      if (c0 > trow) s0 = -1e30f;
      if (c1 > trow) s1 = -1e30f;
      float m = fmaxf(s0, s1);
      #pragma unroll
      for (int d = 1; d < 16; d <<= 1) m = fmaxf(m, __shfl_xor(m, d));
      float e0 = __expf(s0 - m), e1 = __expf(s1 - m);
      float sum = e0 + e1;
      #pragma unroll
      for (int d = 1; d < 16; d <<= 1) sum += __shfl_xor(sum, d);
      float inv = 1.f / sum;
      p_s[w][trow][c0] = f2b(e0 * inv);
      p_s[w][trow][c1] = f2b(e1 * inv);
    }

  // O = P V
  bf8 b_v = *(const bf8*)(&v_s[w][lane & 15][(lane >> 4) * 8]);
  f4 o_[2] = {};
  #pragma unroll
  for (int mt = 0; mt < 2; ++mt) {
    bf8 a_p = *(const bf8*)(&p_s[w][mt * 16 + (lane & 15)][(lane >> 4) * 8]);
    o_[mt] = __builtin_amdgcn_mfma_f32_16x16x32_bf16(a_p, b_v, o_[mt], 0, 0, 0);
  }
  #pragma unroll
  for (int mt = 0; mt < 2; ++mt)
    #pragma unroll
    for (int rr = 0; rr < 4; ++rr)
      o_s[mt * 16 + (lane >> 4) * 4 + rr][w * 16 + (lane & 15)] = f2b(o_[mt][rr]);
  __syncthreads();

  // OUT = O @ Wo^T + residual
  bf8 a_o[2][2];
  #pragma unroll
  for (int mt = 0; mt < 2; ++mt)
    #pragma unroll
    for (int kk = 0; kk < 2; ++kk)
      a_o[mt][kk] = *(const bf8*)(&o_s[mt * 16 + (lane & 15)][kk * 32 + (lane >> 4) * 8]);
  f4 oo[2] = {};
  #pragma unroll
  for (int kk = 0; kk < 2; ++kk)
    #pragma unroll
    for (int mt = 0; mt < 2; ++mt)
      oo[mt] = __builtin_amdgcn_mfma_f32_16x16x32_bf16(a_o[mt][kk], wof[kk], oo[mt], 0, 0, 0);
  #pragma unroll
  for (int mt = 0; mt < 2; ++mt)
    #pragma unroll
    for (int rr = 0; rr < 4; ++rr) {
      int row = mt * 16 + (lane >> 4) * 4 + rr;
      int col = w * 16 + (lane & 15);
      float resid = b2f(r[(n * 32 + row) * 64 + col]);
      ln_s[row][col] = oo[mt][rr] + resid;
    }
  __syncthreads();

  // LayerNorm over 64 features, write enc (bf16)
  {
    int row = tid >> 3, seg = tid & 7;
    float vals[8], sm = 0.f, sq = 0.f;
    #pragma unroll
    for (int j = 0; j < 8; ++j) {
      float v = ln_s[row][seg * 8 + j];
      vals[j] = v; sm += v; sq += v * v;
    }
    #pragma unroll
    for (int d = 1; d < 8; d <<= 1) { sm += __shfl_xor(sm, d); sq += __shfl_xor(sq, d); }
    float mu = sm * (1.f / 64.f);
    float var = sq * (1.f / 64.f) - mu * mu;
    float rs = rsqrtf(var + 1e-6f);
    union { ushort u[8]; int4 v; } ou;
    #pragma unroll
    for (int j = 0; j < 8; ++j) {
      int c = seg * 8 + j;
      ou.u[j] = f2b((vals[j] - mu) * rs * lng[c] + lnb[c]);
    }
    *(int4*)(enc + (n * 32 + row) * 64 + seg * 8) = ou.v;
  }
}

// ---------------- final projection (n_hid=128 -> 2) ----------------
__global__ __launch_bounds__(256) void final_k(const float* __restrict__ hg3,
                                               const float* __restrict__ Wp,
                                               float* __restrict__ out) {
  int i = blockIdx.x * 256 + threadIdx.x;
  if (i >= 8192) return;
  const float* row = hg3 + (size_t)i * 128;
  float a0 = 0.f, a1 = 0.f;
  #pragma unroll
  for (int k = 0; k < 128; k += 4) {
    f4 h  = *(const f4*)(row + k);
    f4 w0 = *(const f4*)(Wp + k);
    f4 w1 = *(const f4*)(Wp + 128 + k);
    a0 += h[0] * w0[0] + h[1] * w0[1] + h[2] * w0[2] + h[3] * w0[3];
    a1 += h[0] * w1[0] + h[1] * w1[1] + h[2] * w1[2] + h[3] * w1[3];
  }
  out[i * 2] = a0; out[i * 2 + 1] = a1;
}

extern "C" void kernel_launch(void* const* d_in, const int* in_sizes, int n_in,
                              void* d_out, int out_size, void* d_ws, size_t ws_size,
                              hipStream_t stream) {
  const float* src = (const float*)d_in[0];
  const float* H   = (const float*)d_in[1];
  const float* adj = (const float*)d_in[2];
  const float* gW1 = (const float*)d_in[4];
  const float* gb1 = (const float*)d_in[5];
  const float* gW2 = (const float*)d_in[6];
  const float* gb2 = (const float*)d_in[7];
  const float* Wm  = (const float*)d_in[8];
  const float* bm  = (const float*)d_in[9];
  const float* Wl  = (const float*)d_in[10];
  const float* bl  = (const float*)d_in[11];
  const float* Wx0 = (const float*)d_in[12];
  const float* Wh0 = (const float*)d_in[13];
  const float* bx0 = (const float*)d_in[14];
  const float* bh0 = (const float*)d_in[15];
  const float* Wx1 = (const float*)d_in[16];
  const float* Wh1 = (const float*)d_in[17];
  const float* bx1 = (const float*)d_in[18];
  const float* bh1 = (const float*)d_in[19];
  const float* Wq  = (const float*)d_in[20];
  const float* Wk  = (const float*)d_in[21];
  const float* Wv  = (const float*)d_in[22];
  const float* Wo  = (const float*)d_in[23];
  const float* lng = (const float*)d_in[24];
  const float* lnb = (const float*)d_in[25];
  const float* Wg1 = (const float*)d_in[26];
  const float* Wg2 = (const float*)d_in[27];
  const float* Wp  = (const float*)d_in[28];

  char* ws = (char*)d_ws;
  const size_t MiB = 1048576ull;
  ushort* adj_bf = (ushort*)(ws);
  ushort* Hnew_bf = (ushort*)(ws + 2 * MiB);
  ushort* H_bf   = (ushort*)(ws + 4 * MiB);
  ushort* Wm_bf  = (ushort*)(ws + 4 * MiB + 262144);
  ushort* Wg1_bf = (ushort*)(ws + 4 * MiB + 524288);
  ushort* W1_bf  = (ushort*)(ws + 5 * MiB);
  ushort* W2_bf  = (ushort*)(ws + 5 * MiB + 16384);
  ushort* Wl_bf  = (ushort*)(ws + 5 * MiB + 32768);
  ushort* Wg2_bf = (ushort*)(ws + 5 * MiB + 49152);
  ushort* XW1   = (ushort*)(ws + 6 * MiB);    // 64 MiB, later reused as z_bf
  ushort* z_bf  = XW1;
  ushort* hbuf  = (ushort*)(ws + 70 * MiB);   // 64 MiB, later x_bf (+0) and r_bf (+32MiB)
  ushort* x_bf  = hbuf;
  ushort* r_bf  = (ushort*)(ws + 102 * MiB);
  float*  zacc  = (float*)(ws + 134 * MiB);   // 64 MiB f32, shares region with src_bf/enc/HGN
  ushort* src_bf = (ushort*)(ws + 134 * MiB); // 32 MiB (dead before zacc written)
  ushort* enc   = (ushort*)(ws + 134 * MiB);  // 32 MiB (after zacc dead)
  ushort* g1    = (ushort*)(ws + 166 * MiB);
  ushort* hg    = (ushort*)(ws + 168 * MiB);
  ushort* hg2   = (ushort*)(ws + 170 * MiB);
  float*  hg3   = (float*)(ws + 172 * MiB);
  ushort* t2    = (ushort*)(ws + 198 * MiB);  // 32 MiB

  auto CVT = [&](const float* in, ushort* out, int n) {
    int n4 = n >> 2;
    cvt_k<<<dim3((n4 + 255) / 256), dim3(256), 0, stream>>>(in, out, n4);
  };
  CVT(src, src_bf, 16777216);
  CVT(adj, adj_bf, 1048576);
  CVT(H, H_bf, 131072);
  CVT(Wm, Wm_bf, 131072);
  CVT(gW1, W1_bf, 8192);
  CVT(gW2, W2_bf, 8192);
  CVT(Wl, Wl_bf, 4096);
  CVT(Wg1, Wg1_bf, 262144);
  CVT(Wg2, Wg2_bf, 16384);

  // H_new = H @ Wm^T + bm           (1024x1024)
  gemm_k<1,1,0,0,1><<<dim3(8,8,1),256,0,stream>>>(H_bf, Wm_bf, Hnew_bf, nullptr, bm, 1023,
      1024,1024,128, 128,128,1024, 0,0,0);
  // XW1 = src @ W1                  (262144x128)
  gemm_k<0,0,0,0,1><<<dim3(2048,1,1),256,0,stream>>>(src_bf, W1_bf, XW1, nullptr, nullptr, 0,
      262144,128,64, 64,128,128, 0,0,0);
  // branch adj: h = relu(adj @ XW1 + b1)
  gemm_k<0,1,1,0,1><<<dim3(8,32,8),256,0,stream>>>(adj_bf, XW1, hbuf, nullptr, gb1, 127,
      1024,4096,1024, 1024,4096,4096, 4194304,4194304,0);
  // t2 = h @ W2
  gemm_k<0,0,0,0,1><<<dim3(2048,1,1),256,0,stream>>>(hbuf, W2_bf, t2, nullptr, nullptr, 0,
      262144,64,128, 128,64,64, 0,0,0);
  // zacc = adj @ t2 + b2   (f32)
  gemm_k<0,1,0,0,0><<<dim3(8,16,8),256,0,stream>>>(adj_bf, t2, zacc, nullptr, gb2, 63,
      1024,2048,1024, 1024,2048,2048, 2097152,2097152,0);
  // branch H_new
  gemm_k<0,1,1,0,1><<<dim3(8,32,8),256,0,stream>>>(Hnew_bf, XW1, hbuf, nullptr, gb1, 127,
      1024,4096,1024, 1024,4096,4096, 4194304,4194304,0);
  gemm_k<0,0,0,0,1><<<dim3(2048,1,1),256,0,stream>>>(hbuf, W2_bf, t2, nullptr, nullptr, 0,
      262144,64,128, 128,64,64, 0,0,0);
  // z = H_new @ t2 + b2 + zacc  -> bf16 (overwrites XW1 region)
  gemm_k<0,1,0,1,1><<<dim3(8,16,8),256,0,stream>>>(Hnew_bf, t2, z_bf, zacc, gb2, 63,
      1024,2048,1024, 1024,2048,2048, 2097152,2097152,2097152);
  // x = z @ Wl^T + bl
  gemm_k<1,1,0,0,1><<<dim3(2048,1,1),256,0,stream>>>(z_bf, Wl_bf, x_bf, nullptr, bl, 63,
      262144,64,64, 64,64,64, 0,0,0);
  // 2-layer GRU
  gru_k<<<dim3(256),dim3(256),0,stream>>>(x_bf, Wx0,Wh0,bx0,bh0, Wx1,Wh1,bx1,bh1, r_bf);
  // fused attention + residual + LN -> enc
  attn_k<<<dim3(8192),dim3(256),0,stream>>>(r_bf, Wq,Wk,Wv,Wo, lng,lnb, enc);
  // HGN
  gemm_k<0,0,0,0,1><<<dim3(64,1,1),256,0,stream>>>(enc, Wg1_bf, g1, nullptr, nullptr, 0,
      8192,128,2048, 2048,128,128, 0,0,0);
  gemm_k<0,0,1,0,1><<<dim3(8,1,8),256,0,stream>>>(adj_bf, g1, hg, nullptr, nullptr, 0,
      1024,128,1024, 1024,128,128, 131072,131072,0);
  gemm_k<0,0,0,0,1><<<dim3(64,1,1),256,0,stream>>>(hg, Wg2_bf, hg2, nullptr, nullptr, 0,
      8192,128,128, 128,128,128, 0,0,0);
  gemm_k<0,0,0,0,0><<<dim3(8,1,8),256,0,stream>>>(adj_bf, hg2, hg3, nullptr, nullptr, 0,
      1024,128,1024, 1024,128,128, 131072,131072,0);
  // out = hg3 @ Wp^T
  final_k<<<dim3(32),dim3(256),0,stream>>>(hg3, Wp, (float*)d_out);
}

// Round 2
// 814.068 us; speedup vs baseline: 1.8938x; 1.8938x over previous
//
#include <hip/hip_runtime.h>

typedef __attribute__((ext_vector_type(8))) short bf8;
typedef __attribute__((ext_vector_type(4))) float f4;

__device__ __forceinline__ ushort f2b(float f) {
  union { float f; unsigned u; } v; v.f = f;
  unsigned u = v.u + 0x7FFFu + ((v.u >> 16) & 1u);
  return (ushort)(u >> 16);
}
__device__ __forceinline__ float b2f(ushort h) {
  union { unsigned u; float f; } v; v.u = ((unsigned)h) << 16; return v.f;
}
__device__ __forceinline__ bf8 pack8(const float* p) {
  f4 a = *(const f4*)p; f4 b = *(const f4*)(p + 4);
  bf8 t;
  t[0] = (short)f2b(a[0]); t[1] = (short)f2b(a[1]);
  t[2] = (short)f2b(a[2]); t[3] = (short)f2b(a[3]);
  t[4] = (short)f2b(b[0]); t[5] = (short)f2b(b[1]);
  t[6] = (short)f2b(b[2]); t[7] = (short)f2b(b[3]);
  return t;
}
__device__ __forceinline__ float sigm(float x) { return 1.f / (1.f + __expf(-x)); }
__device__ __forceinline__ float tanh_f(float x) {
  float a = fabsf(x), e = __expf(-2.f * a);
  return copysignf((1.f - e) / (1.f + e), x);
}

// async global->LDS, 16B per lane; LDS dest = wave-uniform base + lane*16
__device__ __forceinline__ void gl16(const void* g, void* l) {
  __builtin_amdgcn_global_load_lds(
      (const __attribute__((address_space(1))) unsigned int*)(uintptr_t)g,
      (__attribute__((address_space(3))) unsigned int*)(uintptr_t)l, 16, 0, 0);
}

// ---------------- f32 -> bf16 convert ----------------
__global__ __launch_bounds__(256) void cvt_k(const float* __restrict__ in,
                                             ushort* __restrict__ out, int n4) {
  int i = blockIdx.x * 256 + threadIdx.x;
  if (i < n4) {
    f4 v = ((const f4*)in)[i];
    ushort4 o;
    o.x = f2b(v[0]); o.y = f2b(v[1]); o.z = f2b(v[2]); o.w = f2b(v[3]);
    ((ushort4*)out)[i] = o;
  }
}

// ---------------- f32 -> bf16 transposing convert: in (R,C) -> out (C,R) ----
__global__ __launch_bounds__(256) void cvtT_k(const float* __restrict__ in,
                                              ushort* __restrict__ out, int R, int C) {
  __shared__ ushort t[64][68];
  const int tid = threadIdx.x;
  const int r0 = blockIdx.x * 64, c0 = blockIdx.y * 64;
  #pragma unroll
  for (int it = 0; it < 4; ++it) {
    int r = (tid >> 4) + 16 * it, c = (tid & 15) * 4;
    f4 v = *(const f4*)(in + (long)(r0 + r) * C + c0 + c);
    #pragma unroll
    for (int j = 0; j < 4; ++j) t[c + j][r] = f2b(v[j]);
  }
  __syncthreads();
  #pragma unroll
  for (int it = 0; it < 4; ++it) {
    int cc = (tid >> 4) + 16 * it, rr = (tid & 15) * 4;
    ushort4 o = { t[cc][rr], t[cc][rr + 1], t[cc][rr + 2], t[cc][rr + 3] };
    *(ushort4*)(out + (long)(c0 + cc) * R + r0 + rr) = o;
  }
}

// ---------------- tiny weight-fusion kernels ----------------
// WcombT[d][h] = sum_f Wl[d,f] * W2[h,f]   (64 x 128, bf16)
__global__ void wcombT_k(const float* __restrict__ Wl, const float* __restrict__ W2,
                         ushort* __restrict__ out) {
  int idx = blockIdx.x * 256 + threadIdx.x;  // 8192
  int d = idx >> 7, h = idx & 127;
  float s = 0.f;
  #pragma unroll
  for (int f = 0; f < 64; ++f) s += Wl[d * 64 + f] * W2[h * 64 + f];
  out[d * 128 + h] = f2b(s);
}
// bc[d] = 2*sum_f b2[f]*Wl[d,f] + bl[d]
__global__ void biasc_k(const float* __restrict__ gb2, const float* __restrict__ Wl,
                        const float* __restrict__ bl, float* __restrict__ bc) {
  int d = threadIdx.x;  // 64
  float s = 0.f;
  #pragma unroll
  for (int f = 0; f < 64; ++f) s += gb2[f] * Wl[d * 64 + f];
  bc[d] = 2.f * s + bl[d];
}
// Wfin[d*2+c] = sum_e Wg2[d,e]*Wp[c,e]
__global__ void wfin_k(const float* __restrict__ Wg2, const float* __restrict__ Wp,
                       float* __restrict__ wf) {
  int idx = threadIdx.x;  // 256
  int d = idx >> 1, c = idx & 1;
  float s = 0.f;
  #pragma unroll
  for (int e = 0; e < 128; ++e) s += Wg2[d * 128 + e] * Wp[c * 128 + e];
  wf[idx] = s;
}

// ---------------- bf16 MFMA GEMM (all-TRANSB=1 form) ----------------
// C[row, col] = op( sum_k A[row,k] * B[col,k] )
// A (M x K) row-major, B (N x K) row-major. global_load_lds staging with
// XOR-pre-swizzled source + swizzled ds_read (linear LDS, conflict-free).
// BIASMODE: 0 none, 1 by col, 2 by row. FULLB=0: guarded reg-staging for B
// (needed when N < 128).
template<int BIASMODE, int RELU, int FULLB>
__global__ __launch_bounds__(256) void gemm_k(
    const ushort* __restrict__ A, const ushort* __restrict__ B,
    ushort* __restrict__ C, const float* __restrict__ bias, int biasMask,
    int N, int K, int lda, int ldb, int ldc, int ZD,
    long sAq, long sAr, long sBq, long sBr, long sCq, long sCr)
{
  __shared__ __align__(16) ushort As[128 * 64];
  __shared__ __align__(16) ushort Bs[128 * 64];
  const int tid = threadIdx.x, lane = tid & 63, wv = tid >> 6;
  const int wm = wv >> 1, wn = wv & 1;
  const long bm = (long)blockIdx.x * 128, bn = (long)blockIdx.y * 128;
  int z = blockIdx.z, zq = z, zr = 0;
  if (ZD > 1) { zq = z / ZD; zr = z - zq * ZD; }
  const ushort* Ap = A + (long)zq * sAq + (long)zr * sAr + bm * lda;
  const ushort* Bp = B + (long)zq * sBq + (long)zr * sBr + bn * ldb;
  ushort* Cp = C + (long)zq * sCq + (long)zr * sCr;
  f4 acc[4][4] = {};
  for (int k0 = 0; k0 < K; k0 += 64) {
    #pragma unroll
    for (int i = 0; i < 4; ++i) {
      int row = wv * 32 + i * 8 + (lane >> 3);
      int gc = k0 + (((lane & 7) ^ (row & 7)) << 3);
      gl16(Ap + (long)row * lda + gc, &As[(wv * 32 + i * 8) * 64]);
    }
    if (FULLB) {
      #pragma unroll
      for (int i = 0; i < 4; ++i) {
        int row = wv * 32 + i * 8 + (lane >> 3);
        int gc = k0 + (((lane & 7) ^ (row & 7)) << 3);
        gl16(Bp + (long)row * ldb + gc, &Bs[(wv * 32 + i * 8) * 64]);
      }
    } else {
      #pragma unroll
      for (int i = 0; i < 4; ++i) {
        int row = (tid >> 3) + 32 * i;
        int b8 = tid & 7;
        int4 v = {0, 0, 0, 0};
        if (bn + row < N) v = *(const int4*)(Bp + (long)row * ldb + k0 + ((b8 ^ (row & 7)) << 3));
        *(int4*)(&Bs[row * 64 + b8 * 8]) = v;
      }
    }
    __syncthreads();
    bf8 af[4][2], bfv[4][2];
    #pragma unroll
    for (int mi = 0; mi < 4; ++mi) {
      int r = wm * 64 + mi * 16 + (lane & 15);
      #pragma unroll
      for (int kk = 0; kk < 2; ++kk) {
        int blk = kk * 4 + (lane >> 4);
        af[mi][kk] = *(const bf8*)(&As[r * 64 + ((blk ^ (r & 7)) << 3)]);
      }
    }
    #pragma unroll
    for (int ni = 0; ni < 4; ++ni) {
      int r = wn * 64 + ni * 16 + (lane & 15);
      #pragma unroll
      for (int kk = 0; kk < 2; ++kk) {
        int blk = kk * 4 + (lane >> 4);
        bfv[ni][kk] = *(const bf8*)(&Bs[r * 64 + ((blk ^ (r & 7)) << 3)]);
      }
    }
    #pragma unroll
    for (int kk = 0; kk < 2; ++kk)
      #pragma unroll
      for (int mi = 0; mi < 4; ++mi)
        #pragma unroll
        for (int ni = 0; ni < 4; ++ni)
          acc[mi][ni] = __builtin_amdgcn_mfma_f32_16x16x32_bf16(af[mi][kk], bfv[ni][kk], acc[mi][ni], 0, 0, 0);
    __syncthreads();
  }
  #pragma unroll
  for (int mi = 0; mi < 4; ++mi)
    #pragma unroll
    for (int ni = 0; ni < 4; ++ni) {
      int col = (int)bn + wn * 64 + ni * 16 + (lane & 15);
      if (col < N) {
        #pragma unroll
        for (int rr = 0; rr < 4; ++rr) {
          int row = (int)bm + wm * 64 + mi * 16 + (lane >> 4) * 4 + rr;
          float v = acc[mi][ni][rr];
          if (BIASMODE == 1) v += bias[col & biasMask];
          if (BIASMODE == 2) v += bias[row & biasMask];
          if (RELU) v = fmaxf(v, 0.f);
          Cp[(long)row * ldc + col] = f2b(v);
        }
      }
    }
}

// ---------------- transpose+add: PsT (b, th, s) x2 -> Psum (b,s,t,h) -------
__global__ __launch_bounds__(256) void tadd_k(const ushort* __restrict__ P1,
                                              const ushort* __restrict__ P2,
                                              ushort* __restrict__ Ps) {
  __shared__ ushort ls[64][72];
  const int tid = threadIdx.x;
  const int t = blockIdx.x >> 1, h0 = (blockIdx.x & 1) * 64;
  const long th0 = (long)blockIdx.x * 64;
  const int s0 = blockIdx.y * 64, b = blockIdx.z;
  const long ibase = (long)b * 4194304 + th0 * 1024 + s0;
  #pragma unroll
  for (int it = 0; it < 2; ++it) {
    int r = (tid >> 3) + 32 * it, c8 = tid & 7;
    long off = ibase + (long)r * 1024 + c8 * 8;
    int4 v1 = *(const int4*)(P1 + off);
    int4 v2 = *(const int4*)(P2 + off);
    ushort* u1 = (ushort*)&v1; ushort* u2 = (ushort*)&v2;
    ushort o[8];
    #pragma unroll
    for (int j = 0; j < 8; ++j) o[j] = f2b(b2f(u1[j]) + b2f(u2[j]));
    *(int4*)(&ls[r][c8 * 8]) = *(int4*)o;
  }
  __syncthreads();
  #pragma unroll
  for (int it = 0; it < 2; ++it) {
    int sr = (tid >> 3) + 32 * it, hc8 = tid & 7;
    ushort u[8];
    #pragma unroll
    for (int k = 0; k < 8; ++k) {
      int j = (k + hc8) & 7;             // rotate to avoid bank conflicts
      u[j] = ls[hc8 * 8 + j][sr];
    }
    long orow = ((long)(b * 1024 + s0 + sr) * 32 + t) * 128 + h0 + hc8 * 8;
    *(int4*)(Ps + orow) = *(int4*)u;
  }
}

// ---------------- fused 2-layer GRU (unchanged, verified) ----------------
__global__ __launch_bounds__(256) void gru_k(
    const ushort* __restrict__ x,
    const float* __restrict__ Wx0, const float* __restrict__ Wh0,
    const float* __restrict__ bx0, const float* __restrict__ bh0,
    const float* __restrict__ Wx1, const float* __restrict__ Wh1,
    const float* __restrict__ bx1, const float* __restrict__ bh1,
    ushort* __restrict__ rout)
{
  __shared__ ushort hbf[2][32][88];
  __shared__ float  hf[2][32][68];
  const int tid = threadIdx.x, lane = tid & 63, w = tid >> 6;
  const long seq0 = (long)blockIdx.x * 32;
  for (int i = tid; i < 2 * 32 * 88; i += 256) ((ushort*)hbf)[i] = 0;
  for (int i = tid; i < 2 * 32 * 68; i += 256) ((float*)hf)[i] = 0.f;

  const float* Wxp[2] = {Wx0, Wx1};
  const float* Whp[2] = {Wh0, Wh1};
  const float* bxp[2] = {bx0, bx1};
  const float* bhp[2] = {bh0, bh1};
  bf8 Wxf[2][3][2], Whf[2][3][2];
  float bxv[2][3], bhv[2][3];
  #pragma unroll
  for (int L = 0; L < 2; ++L)
    #pragma unroll
    for (int g = 0; g < 3; ++g) {
      int row = g * 64 + w * 16 + (lane & 15);
      bxv[L][g] = bxp[L][row];
      bhv[L][g] = bhp[L][row];
      #pragma unroll
      for (int kk = 0; kk < 2; ++kk) {
        int kb = kk * 32 + (lane >> 4) * 8;
        Wxf[L][g][kk] = pack8(Wxp[L] + row * 64 + kb);
        Whf[L][g][kk] = pack8(Whp[L] + row * 64 + kb);
      }
    }
  __syncthreads();

  for (int t = 0; t < 32; ++t) {
    #pragma unroll
    for (int L = 0; L < 2; ++L) {
      bf8 ax[2][2], ah[2][2];
      #pragma unroll
      for (int mi = 0; mi < 2; ++mi)
        #pragma unroll
        for (int kk = 0; kk < 2; ++kk) {
          int row = mi * 16 + (lane & 15);
          int kb = kk * 32 + (lane >> 4) * 8;
          if (L == 0) ax[mi][kk] = *(const bf8*)(x + ((seq0 + row) * 32 + t) * 64 + kb);
          else        ax[mi][kk] = *(const bf8*)(&hbf[0][row][kb]);
          ah[mi][kk] = *(const bf8*)(&hbf[L][row][kb]);
        }
      f4 aX[2][3] = {}; f4 aH[2][3] = {};
      #pragma unroll
      for (int kk = 0; kk < 2; ++kk)
        #pragma unroll
        for (int mi = 0; mi < 2; ++mi)
          #pragma unroll
          for (int g = 0; g < 3; ++g) {
            aX[mi][g] = __builtin_amdgcn_mfma_f32_16x16x32_bf16(ax[mi][kk], Wxf[L][g][kk], aX[mi][g], 0, 0, 0);
            aH[mi][g] = __builtin_amdgcn_mfma_f32_16x16x32_bf16(ah[mi][kk], Whf[L][g][kk], aH[mi][g], 0, 0, 0);
          }
      __syncthreads();
      #pragma unroll
      for (int mi = 0; mi < 2; ++mi)
        #pragma unroll
        for (int r = 0; r < 4; ++r) {
          int row = mi * 16 + (lane >> 4) * 4 + r;
          int col = w * 16 + (lane & 15);
          float rg = sigm(aX[mi][0][r] + bxv[L][0] + aH[mi][0][r] + bhv[L][0]);
          float zg = sigm(aX[mi][1][r] + bxv[L][1] + aH[mi][1][r] + bhv[L][1]);
          float hn = aH[mi][2][r] + bhv[L][2];
          float cand = tanh_f(aX[mi][2][r] + bxv[L][2] + rg * hn);
          float hp = hf[L][row][col];
          float hnew = (1.f - zg) * cand + zg * hp;
          hf[L][row][col] = hnew;
          ushort hb = f2b(hnew);
          hbf[L][row][col] = hb;
          if (L == 1) rout[((seq0 + row) * 32 + t) * 64 + col] = hb;
        }
      __syncthreads();
    }
  }
}

// ------------- fused temporal attention + residual + LayerNorm (unchanged) --
__global__ __launch_bounds__(256) void attn_k(
    const ushort* __restrict__ r,
    const float* __restrict__ Wq, const float* __restrict__ Wk,
    const float* __restrict__ Wv, const float* __restrict__ Wo,
    const float* __restrict__ lng, const float* __restrict__ lnb,
    ushort* __restrict__ enc)
{
  __shared__ ushort q_s[4][32][40];
  __shared__ ushort k_s[4][32][40];
  __shared__ ushort v_s[4][16][40];
  __shared__ ushort p_s[4][32][40];
  __shared__ ushort o_s[32][88];
  __shared__ float  ln_s[32][68];
  const int tid = threadIdx.x, lane = tid & 63, w = tid >> 6;
  const long n = blockIdx.x;

  for (int i = tid; i < 4 * 32 * 40; i += 256) { ((ushort*)q_s)[i] = 0; ((ushort*)k_s)[i] = 0; }

  bf8 wqf[2], wkf[2], wvf[2], wof[2];
  #pragma unroll
  for (int kk = 0; kk < 2; ++kk) {
    int row = w * 16 + (lane & 15);
    int kb = kk * 32 + (lane >> 4) * 8;
    wqf[kk] = pack8(Wq + row * 64 + kb);
    wkf[kk] = pack8(Wk + row * 64 + kb);
    wvf[kk] = pack8(Wv + row * 64 + kb);
    wof[kk] = pack8(Wo + row * 64 + kb);
  }
  __syncthreads();

  bf8 ar[2][2];
  #pragma unroll
  for (int mi = 0; mi < 2; ++mi)
    #pragma unroll
    for (int kk = 0; kk < 2; ++kk)
      ar[mi][kk] = *(const bf8*)(r + (n * 32 + mi * 16 + (lane & 15)) * 64 + kk * 32 + (lane >> 4) * 8);
  f4 aq[2] = {}, ak[2] = {}, av[2] = {};
  #pragma unroll
  for (int kk = 0; kk < 2; ++kk)
    #pragma unroll
    for (int mi = 0; mi < 2; ++mi) {
      aq[mi] = __builtin_amdgcn_mfma_f32_16x16x32_bf16(ar[mi][kk], wqf[kk], aq[mi], 0, 0, 0);
      ak[mi] = __builtin_amdgcn_mfma_f32_16x16x32_bf16(ar[mi][kk], wkf[kk], ak[mi], 0, 0, 0);
      av[mi] = __builtin_amdgcn_mfma_f32_16x16x32_bf16(ar[mi][kk], wvf[kk], av[mi], 0, 0, 0);
    }
  #pragma unroll
  for (int mi = 0; mi < 2; ++mi)
    #pragma unroll
    for (int rr = 0; rr < 4; ++rr) {
      int row = mi * 16 + (lane >> 4) * 4 + rr;
      q_s[w][row][lane & 15] = f2b(aq[mi][rr]);
      k_s[w][row][lane & 15] = f2b(ak[mi][rr]);
      v_s[w][lane & 15][row] = f2b(av[mi][rr]);
    }

  bf8 a_q[2], b_k[2];
  #pragma unroll
  for (int mt = 0; mt < 2; ++mt)
    a_q[mt] = *(const bf8*)(&q_s[w][mt * 16 + (lane & 15)][(lane >> 4) * 8]);
  #pragma unroll
  for (int nt = 0; nt < 2; ++nt)
    b_k[nt] = *(const bf8*)(&k_s[w][nt * 16 + (lane & 15)][(lane >> 4) * 8]);
  f4 s_[2][2] = {};
  #pragma unroll
  for (int mt = 0; mt < 2; ++mt)
    #pragma unroll
    for (int nt = 0; nt < 2; ++nt)
      s_[mt][nt] = __builtin_amdgcn_mfma_f32_16x16x32_bf16(a_q[mt], b_k[nt], s_[mt][nt], 0, 0, 0);
  #pragma unroll
  for (int mt = 0; mt < 2; ++mt)
    #pragma unroll
    for (int rr = 0; rr < 4; ++rr) {
      int trow = mt * 16 + (lane >> 4) * 4 + rr;
      float s0 = s_[mt][0][rr] * 0.25f, s1 = s_[mt][1][rr] * 0.25f;
      int c0 = lane & 15, c1 = 16 + (lane & 15);
      if (c0 > trow) s0 = -1e30f;
      if (c1 > trow) s1 = -1e30f;
      float m = fmaxf(s0, s1);
      #pragma unroll
      for (int d = 1; d < 16; d <<= 1) m = fmaxf(m, __shfl_xor(m, d));
      float e0 = __expf(s0 - m), e1 = __expf(s1 - m);
      float sum = e0 + e1;
      #pragma unroll
      for (int d = 1; d < 16; d <<= 1) sum += __shfl_xor(sum, d);
      float inv = 1.f / sum;
      p_s[w][trow][c0] = f2b(e0 * inv);
      p_s[w][trow][c1] = f2b(e1 * inv);
    }

  bf8 b_v = *(const bf8*)(&v_s[w][lane & 15][(lane >> 4) * 8]);
  f4 o_[2] = {};
  #pragma unroll
  for (int mt = 0; mt < 2; ++mt) {
    bf8 a_p = *(const bf8*)(&p_s[w][mt * 16 + (lane & 15)][(lane >> 4) * 8]);
    o_[mt] = __builtin_amdgcn_mfma_f32_16x16x32_bf16(a_p, b_v, o_[mt], 0, 0, 0);
  }
  #pragma unroll
  for (int mt = 0; mt < 2; ++mt)
    #pragma unroll
    for (int rr = 0; rr < 4; ++rr)
      o_s[mt * 16 + (lane >> 4) * 4 + rr][w * 16 + (lane & 15)] = f2b(o_[mt][rr]);
  __syncthreads();

  bf8 a_o[2][2];
  #pragma unroll
  for (int mt = 0; mt < 2; ++mt)
    #pragma unroll
    for (int kk = 0; kk < 2; ++kk)
      a_o[mt][kk] = *(const bf8*)(&o_s[mt * 16 + (lane & 15)][kk * 32 + (lane >> 4) * 8]);
  f4 oo[2] = {};
  #pragma unroll
  for (int kk = 0; kk < 2; ++kk)
    #pragma unroll
    for (int mt = 0; mt < 2; ++mt)
      oo[mt] = __builtin_amdgcn_mfma_f32_16x16x32_bf16(a_o[mt][kk], wof[kk], oo[mt], 0, 0, 0);
  #pragma unroll
  for (int mt = 0; mt < 2; ++mt)
    #pragma unroll
    for (int rr = 0; rr < 4; ++rr) {
      int row = mt * 16 + (lane >> 4) * 4 + rr;
      int col = w * 16 + (lane & 15);
      float resid = b2f(r[(n * 32 + row) * 64 + col]);
      ln_s[row][col] = oo[mt][rr] + resid;
    }
  __syncthreads();

  {
    int row = tid >> 3, seg = tid & 7;
    float vals[8], sm = 0.f, sq = 0.f;
    #pragma unroll
    for (int j = 0; j < 8; ++j) {
      float v = ln_s[row][seg * 8 + j];
      vals[j] = v; sm += v; sq += v * v;
    }
    #pragma unroll
    for (int d = 1; d < 8; d <<= 1) { sm += __shfl_xor(sm, d); sq += __shfl_xor(sq, d); }
    float mu = sm * (1.f / 64.f);
    float var = sq * (1.f / 64.f) - mu * mu;
    float rs = rsqrtf(var + 1e-6f);
    union { ushort u[8]; int4 v; } ou;
    #pragma unroll
    for (int j = 0; j < 8; ++j) {
      int c = seg * 8 + j;
      ou.u[j] = f2b((vals[j] - mu) * rs * lng[c] + lnb[c]);
    }
    *(int4*)(enc + (n * 32 + row) * 64 + seg * 8) = ou.v;
  }
}

// ------------- final: out[(b,s),c] = sum_d hg3aT[b][d][s] * Wfin[d,c] -------
__global__ __launch_bounds__(256) void final2_k(const ushort* __restrict__ hg3aT,
                                                const float* __restrict__ wf,
                                                float* __restrict__ out) {
  int i = blockIdx.x * 256 + threadIdx.x;  // 8192
  int b = i >> 10, s = i & 1023;
  const ushort* base = hg3aT + (long)b * 131072 + s;
  float a0 = 0.f, a1 = 0.f;
  #pragma unroll
  for (int d = 0; d < 128; ++d) {
    float v = b2f(base[d * 1024]);
    a0 += v * wf[2 * d];
    a1 += v * wf[2 * d + 1];
  }
  out[2 * i] = a0; out[2 * i + 1] = a1;
}

extern "C" void kernel_launch(void* const* d_in, const int* in_sizes, int n_in,
                              void* d_out, int out_size, void* d_ws, size_t ws_size,
                              hipStream_t stream) {
  const float* src = (const float*)d_in[0];
  const float* H   = (const float*)d_in[1];
  const float* adj = (const float*)d_in[2];
  const float* gW1 = (const float*)d_in[4];
  const float* gb1 = (const float*)d_in[5];
  const float* gW2 = (const float*)d_in[6];
  const float* gb2 = (const float*)d_in[7];
  const float* Wm  = (const float*)d_in[8];
  const float* bm  = (const float*)d_in[9];
  const float* Wl  = (const float*)d_in[10];
  const float* bl  = (const float*)d_in[11];
  const float* Wx0 = (const float*)d_in[12];
  const float* Wh0 = (const float*)d_in[13];
  const float* bx0 = (const float*)d_in[14];
  const float* bh0 = (const float*)d_in[15];
  const float* Wx1 = (const float*)d_in[16];
  const float* Wh1 = (const float*)d_in[17];
  const float* bx1 = (const float*)d_in[18];
  const float* bh1 = (const float*)d_in[19];
  const float* Wq  = (const float*)d_in[20];
  const float* Wk  = (const float*)d_in[21];
  const float* Wv  = (const float*)d_in[22];
  const float* Wo  = (const float*)d_in[23];
  const float* lng = (const float*)d_in[24];
  const float* lnb = (const float*)d_in[25];
  const float* Wg1 = (const float*)d_in[26];
  const float* Wg2 = (const float*)d_in[27];
  const float* Wp  = (const float*)d_in[28];

  char* ws = (char*)d_ws;
  const size_t MB = 1048576ull;
  ushort* adj_bf  = (ushort*)(ws);
  ushort* Hnew_bf = (ushort*)(ws + 2 * MB);
  ushort* H_bf    = (ushort*)(ws + 4 * MB);
  ushort* Wm_bf   = (ushort*)(ws + 4 * MB + 262144);
  ushort* W1T     = (ushort*)(ws + 4 * MB + 524288);
  ushort* WcT     = (ushort*)(ws + 4 * MB + 524288 + 16384);
  float*  bc      = (float*) (ws + 4 * MB + 524288 + 32768);
  float*  wfin    = (float*) (ws + 4 * MB + 524288 + 33792);
  ushort* Wg1T    = (ushort*)(ws + 5 * MB);
  ushort* src_bf  = (ushort*)(ws + 6 * MB);     // 32 MB, dead after XT
  ushort* XT      = (ushort*)(ws + 38 * MB);    // 64 MB
  ushort* h1aT    = (ushort*)(ws + 102 * MB);   // 64 MB
  ushort* h1hT    = (ushort*)(ws + 166 * MB);   // 64 MB
  ushort* P1T     = (ushort*)(ws + 38 * MB);    // over XT (dead)
  ushort* P2T     = (ushort*)(ws + 102 * MB);   // over h1aT (dead)
  ushort* Psum    = (ushort*)(ws + 166 * MB);   // over h1hT (dead)
  ushort* x_bf    = (ushort*)(ws + 38 * MB);    // over P1T (dead)
  ushort* r_bf    = (ushort*)(ws + 70 * MB);
  ushort* enc     = (ushort*)(ws + 102 * MB);   // over P2T (dead)
  ushort* g1T     = (ushort*)(ws + 134 * MB);
  ushort* hgT     = (ushort*)(ws + 136 * MB);
  ushort* hg3aT   = (ushort*)(ws + 138 * MB);

  auto CVT = [&](const float* in, ushort* out, int n) {
    int n4 = n >> 2;
    cvt_k<<<dim3((n4 + 255) / 256), dim3(256), 0, stream>>>(in, out, n4);
  };
  CVT(src, src_bf, 16777216);
  CVT(adj, adj_bf, 1048576);
  CVT(H, H_bf, 131072);
  CVT(Wm, Wm_bf, 131072);
  cvtT_k<<<dim3(1, 2), 256, 0, stream>>>(gW1, W1T, 64, 128);      // W1T (128x64)
  cvtT_k<<<dim3(32, 2), 256, 0, stream>>>(Wg1, Wg1T, 2048, 128);  // Wg1T (128x2048)
  wcombT_k<<<dim3(32), 256, 0, stream>>>(Wl, gW2, WcT);
  biasc_k<<<dim3(1), 64, 0, stream>>>(gb2, Wl, bl, bc);
  wfin_k<<<dim3(1), 256, 0, stream>>>(Wg2, Wp, wfin);

  // H_new = H @ Wm^T + bm   (1024 x 1024)
  gemm_k<1,0,1><<<dim3(8,8,1),256,0,stream>>>(H_bf, Wm_bf, Hnew_bf, bm, 1023,
      1024, 128, 128, 128, 1024, 1, 0,0, 0,0, 0,0);
  // XT[b][t*128+h][s] = (src@W1)^T  — per (b,t): C[h,s] = sum_f W1T[h,f]*src[b,s,t,f]
  gemm_k<0,0,1><<<dim3(1,8,256),256,0,stream>>>(W1T, src_bf, XT, nullptr, 0,
      1024, 64, 64, 2048, 1024, 32, 0,0, 2097152,64, 4194304,131072);
  // layer-1 props: h1T = relu(XT @ A^T + b1[row&127])
  gemm_k<2,1,1><<<dim3(32,8,8),256,0,stream>>>(XT, adj_bf, h1aT, gb1, 127,
      1024, 1024, 1024, 1024, 1024, 1, 4194304,0, 0,0, 4194304,0);
  gemm_k<2,1,1><<<dim3(32,8,8),256,0,stream>>>(XT, Hnew_bf, h1hT, gb1, 127,
      1024, 1024, 1024, 1024, 1024, 1, 4194304,0, 0,0, 4194304,0);
  // layer-2 props (W2 commuted out): P = h1T @ A^T
  gemm_k<0,0,1><<<dim3(32,8,8),256,0,stream>>>(h1aT, adj_bf, P1T, nullptr, 0,
      1024, 1024, 1024, 1024, 1024, 1, 4194304,0, 0,0, 4194304,0);
  gemm_k<0,0,1><<<dim3(32,8,8),256,0,stream>>>(h1hT, Hnew_bf, P2T, nullptr, 0,
      1024, 1024, 1024, 1024, 1024, 1, 4194304,0, 0,0, 4194304,0);
  // Psum(b,s,t,h) = (P1T + P2T) transposed
  tadd_k<<<dim3(64,16,8),256,0,stream>>>(P1T, P2T, Psum);
  // x = Psum @ Wcomb + bias_comb   (262144 x 64), Wcomb = W2@Wl^T
  gemm_k<1,0,0><<<dim3(2048,1,1),256,0,stream>>>(Psum, WcT, x_bf, bc, 63,
      64, 128, 128, 128, 64, 1, 0,0, 0,0, 0,0);
  // GRU + attention
  gru_k<<<dim3(256),dim3(256),0,stream>>>(x_bf, Wx0,Wh0,bx0,bh0, Wx1,Wh1,bx1,bh1, r_bf);
  attn_k<<<dim3(8192),dim3(256),0,stream>>>(r_bf, Wq,Wk,Wv,Wo, lng,lnb, enc);
  // HGN: g1T[b][d][s] = sum_k Wg1T[d,k] * enc[b,s,k]
  gemm_k<0,0,1><<<dim3(1,8,8),256,0,stream>>>(Wg1T, enc, g1T, nullptr, 0,
      1024, 2048, 2048, 2048, 1024, 1, 0,0, 2097152,0, 131072,0);
  // hgT = relu(g1T @ adj^T)
  gemm_k<0,1,1><<<dim3(1,8,8),256,0,stream>>>(g1T, adj_bf, hgT, nullptr, 0,
      1024, 1024, 1024, 1024, 1024, 1, 131072,0, 0,0, 131072,0);
  // hg3aT = hgT @ adj^T   (Wg2 commuted into Wfin)
  gemm_k<0,0,1><<<dim3(1,8,8),256,0,stream>>>(hgT, adj_bf, hg3aT, nullptr, 0,
      1024, 1024, 1024, 1024, 1024, 1, 131072,0, 0,0, 131072,0);
  // out = hg3a @ Wfin
  final2_k<<<dim3(32),256,0,stream>>>(hg3aT, wfin, (float*)d_out);
}